// Round 7
// baseline (3367.458 us; speedup 1.0000x reference)
//
#include <hip/hip_runtime.h>
#include <hip/hip_bf16.h>

typedef __attribute__((ext_vector_type(4))) float f32x4;
typedef __attribute__((ext_vector_type(4))) int   i32x4;
typedef __attribute__((ext_vector_type(8))) short s16x8;
typedef __attribute__((ext_vector_type(4))) unsigned short u16x4;
typedef __attribute__((ext_vector_type(2))) unsigned int  u32x2;
typedef __attribute__((ext_vector_type(2))) unsigned long long u64x2;

#define T_ 512
#define B_ 8
#define H_ 128
#define V_ 32000

// ws layout (bytes)
#define WS_PRE0   0u          // [512][8][128] f32   2MB
#define WS_H1B    (2u<<20)    // [512][8][128] bf16  1MB
#define WS_PIH    (3u<<20)    // [512][8][64] f32x4  4MB
#define WS_FLAGS  (7u<<20)    // prog1 @+0, prog2 @+128

#define GRID_GEMM 500
#define TPB 16                // tiles per gemm block (500*16 = 8000 tiles)

// round-to-nearest-even f32 -> bf16
__device__ __forceinline__ unsigned short f2b(float f) {
  unsigned int u = __float_as_uint(f);
  u = (u + 0x7FFFu + ((u >> 16) & 1u)) >> 16;
  return (unsigned short)u;
}

__device__ __forceinline__ float hsum4(f32x4 v) { return (v.x + v.y) + (v.z + v.w); }

__device__ __forceinline__ float tanh_fast(float x) {
  float e = __expf(2.f * x);
  return 1.f - 2.f * __builtin_amdgcn_rcpf(e + 1.f);
}

__device__ __forceinline__ f32x4 tanh4(f32x4 v) {
  f32x4 r;
  r.x = tanh_fast(v.x); r.y = tanh_fast(v.y);
  r.z = tanh_fast(v.z); r.w = tanh_fast(v.w);
  return r;
}

// pack 4 f32 -> 4 bf16 (2 dwords), RNE
__device__ __forceinline__ u32x2 pk4(f32x4 v) {
  unsigned int a, b;
  asm("v_cvt_pk_bf16_f32 %0, %1, %2" : "=v"(a) : "v"(v.x), "v"(v.y));
  asm("v_cvt_pk_bf16_f32 %0, %1, %2" : "=v"(b) : "v"(v.z), "v"(v.w));
  u32x2 r; r.x = a; r.y = b; return r;
}

// barrier that does NOT drain vmcnt: LDS-only visibility + s_barrier.
__device__ __forceinline__ void lds_barrier() {
  asm volatile("s_waitcnt lgkmcnt(0)\n\ts_barrier" ::: "memory");
}

__device__ __forceinline__ void st_u64(unsigned long long* p, unsigned long long v) {
  __hip_atomic_store(p, v, __ATOMIC_RELAXED, __HIP_MEMORY_SCOPE_AGENT);
}
__device__ __forceinline__ unsigned long long ld_u64(const unsigned long long* p) {
  return __hip_atomic_load(p, __ATOMIC_RELAXED, __HIP_MEMORY_SCOPE_AGENT);
}

#define MFMA16(A, B, C) __builtin_amdgcn_mfma_f32_16x16x32_bf16((A), (B), (C), 0, 0, 0)

__device__ __forceinline__ int swz(int row, int cc) {
  return row * 256 + ((cc ^ (row & 7)) << 4);
}

// ---------------- pre0 = emb[x] @ W_ih0^T + b_ih0 + b_hh0 ----------------
__global__ __launch_bounds__(128) void pre_kernel(const float* __restrict__ emb,
                                                  const int* __restrict__ x,
                                                  const float* __restrict__ W,
                                                  const float* __restrict__ b1,
                                                  const float* __restrict__ b2,
                                                  float* __restrict__ out) {
  const int tid = threadIdx.x;
  __shared__ alignas(16) float lds_in[H_];
  f32x4 w[32];
#pragma unroll
  for (int r = 0; r < 32; ++r) w[r] = *(const f32x4*)(W + tid * H_ + 4 * r);
  const float bsum = b1[tid] + b2[tid];
  const int m0 = blockIdx.x * 16;

  auto src_row = [&](int m) -> const float* {
    int t = m >> 3, b = m & 7;
    int tok = x[(b << 9) + t];          // x is [B,T]
    return emb + (size_t)tok * H_;
  };

  float stage = src_row(m0)[tid];
  for (int rr = 0; rr < 16; ++rr) {
    const int m = m0 + rr;
    lds_in[tid] = stage;
    __syncthreads();
    if (rr + 1 < 16) stage = src_row(m0 + rr + 1)[tid];
    f32x4 acc4 = {0.f, 0.f, 0.f, 0.f};
#pragma unroll
    for (int r = 0; r < 32; ++r) {
      f32x4 hv = *(const f32x4*)(lds_in + 4 * r);
      acc4 = __builtin_elementwise_fma(hv, w[r], acc4);
    }
    out[m * H_ + tid] = hsum4(acc4) + bsum;
    __syncthreads();
  }
}

// ---------------- mega kernel: scan (blocks 0,1) + streamed GEMM (2..501) ----
// block 0: stage0 (h0 recurrence, W_hh0 hi/lo) waves 0-3 + stage1 (pih, hi-only)
//   waves 4-7, barrier-coupled, pih published to global + prog1 (round-6 proven).
// block 1: stage2 (h1 recurrence, W_hh1 hi/lo), pih consumed via depth-4 reg
//   FIFO; acquire-poll batched to once/32 steps (initial 40-step producer lead);
//   publishes prog2 (+32 per 32 steps) after per-wave vmcnt(0)+barrier so h1b
//   stores are agent-visible (release does the L2 writeback).
// blocks 2..501: 16 GEMM tiles each (tb-ascending so every block has early
//   work); per tile: stage fc_W f32->bf16 swizzled LDS, gate on prog2, MFMA,
//   LDS-transposed nontemporal row stores. One-way dep scan->gemm: deadlock-free.
__global__ __launch_bounds__(512, 4) void mega_kernel(
    const float* __restrict__ pre0,
    const float* __restrict__ W_hh0,
    const float* __restrict__ W_ih1,
    const float* __restrict__ W_hh1,
    const float* __restrict__ b_ih1,
    const float* __restrict__ b_hh1,
    unsigned short* __restrict__ h1b,
    unsigned long long* __restrict__ pih_g,
    unsigned int* __restrict__ prog1,
    unsigned int* __restrict__ prog2,
    const float* __restrict__ fc_W,
    const float* __restrict__ fc_b,
    float* __restrict__ out) {
  __shared__ alignas(16) char smem[33792];
  const int bid = blockIdx.x;
  const int tid = threadIdx.x;
  const int wv = tid >> 6, lane = tid & 63;

  if (bid >= 2) {
    // ================= streamed GEMM workers =================
    const int wb = bid - 2;
    const int l15 = lane & 15, lg = lane >> 4;
    int known = 0;
    for (int ti = 0; ti < TPB; ++ti) {
      const int idx = wb + ti * GRID_GEMM;        // sorted tb-major
      const int tb = idx / 2000, r = idx - tb * 2000;
      const int nt = r >> 3, bb = r & 7;
      const int t0 = tb << 7, v0 = nt << 7;

      // stage W tile: f32 -> bf16, swizzled (32KB)
#pragma unroll
      for (int it = 0; it < 4; ++it) {
        int c = it * 512 + tid;
        int row = c >> 4, cc = c & 15;
        const float* src = fc_W + (size_t)(v0 + row) * H_ + cc * 8;
        f32x4 va = *(const f32x4*)src;
        f32x4 vb = *(const f32x4*)(src + 4);
        u32x2 pa = pk4(va), pb = pk4(vb);
        i32x4 w16; w16.x = (int)pa.x; w16.y = (int)pa.y; w16.z = (int)pb.x; w16.w = (int)pb.y;
        *(i32x4*)(smem + swz(row, cc)) = w16;
      }
      // gate on h1 progress (tid 0 polls, acquire-inv covers the block's caches)
      const int need = (tb + 1) * 128;
      if (tid == 0 && known < need) {
        unsigned int p;
        while ((int)(p = __hip_atomic_load(prog2, __ATOMIC_ACQUIRE, __HIP_MEMORY_SCOPE_AGENT)) < need)
          __builtin_amdgcn_s_sleep(64);
        known = (int)p;
      }
      __syncthreads();

      f32x4 acc[8] = {};
#pragma unroll
      for (int kk = 0; kk < 4; ++kk) {
        const int cc = kk * 4 + lg;
        const int trow = t0 + wv * 16 + l15;
        s16x8 bfr = *(const s16x8*)(h1b + (size_t)((trow << 3) + bb) * H_ + kk * 32 + lg * 8);
        s16x8 a[8];
#pragma unroll
        for (int vf = 0; vf < 8; ++vf)
          a[vf] = *(const s16x8*)(smem + swz(vf * 16 + l15, cc));
#pragma unroll
        for (int vf = 0; vf < 8; ++vf)
          acc[vf] = MFMA16(a[vf], bfr, acc[vf]);
      }
#pragma unroll
      for (int vf = 0; vf < 8; ++vf)
        acc[vf] += *(const f32x4*)(fc_b + v0 + vf * 16 + (lg << 2));

      float* tbf = (float*)smem;
#pragma unroll
      for (int p = 0; p < 2; ++p) {
        __syncthreads();
#pragma unroll
        for (int q = 0; q < 4; ++q)
          *(f32x4*)(tbf + (wv * 16 + l15) * 66 + q * 16 + lg * 4) = acc[p * 4 + q];
        __syncthreads();
#pragma unroll
        for (int it = 0; it < 4; ++it) {
          int row = it * 32 + (tid >> 4);
          int col = (tid & 15) * 4;
          f32x4 val = *(const f32x4*)(tbf + row * 66 + col);
          size_t off = (size_t)((bb << 9) + t0 + row) * V_ + v0 + p * 64 + col;
          __builtin_nontemporal_store(val, (f32x4*)(out + off));
        }
      }
      __syncthreads();   // before restaging W over tbf
    }
    return;
  }

  // ================= scan blocks =================
  __builtin_amdgcn_s_setprio(1);   // favor the serial critical path over gemm waves
  typedef unsigned short (*HLP)[16][136];
  HLP hl = (HLP)smem;              // [2][16][136] bf16
  const int n = lane & 15, g = lane >> 4;
  const int nn = (n < 8) ? n : 7;
  for (int i = tid; i < 2 * 16 * 136; i += 512) ((unsigned short*)smem)[i] = 0;

  if (bid == 0) {
    // ---- stage0 (waves 0-3) + stage1 (waves 4-7) ----
    const bool is0 = wv < 4;
    const int w = wv & 3, m0 = w * 32;
    const float* Wm = is0 ? W_hh0 : W_ih1;
    s16x8 whi[2][4], wlo[2][4];
#pragma unroll
    for (int hf = 0; hf < 2; ++hf)
#pragma unroll
      for (int kt = 0; kt < 4; ++kt) {
        const float* src = Wm + (m0 + hf * 16 + n) * H_ + kt * 32 + g * 8;
        s16x8 hi, lo;
#pragma unroll
        for (int j = 0; j < 8; ++j) {
          float v = src[j];
          unsigned short hb = f2b(v);
          hi[j] = (short)hb;
          lo[j] = (short)f2b(v - __uint_as_float(((unsigned int)hb) << 16));
        }
        whi[hf][kt] = hi; wlo[hf][kt] = lo;
      }
    f32x4 c0b = {0.f,0.f,0.f,0.f}, c1b = {0.f,0.f,0.f,0.f};
    if (!is0) {
      c0b = *(const f32x4*)(b_ih1 + m0 + g * 4) + *(const f32x4*)(b_hh1 + m0 + g * 4);
      c1b = *(const f32x4*)(b_ih1 + m0 + 16 + g * 4) + *(const f32x4*)(b_hh1 + m0 + 16 + g * 4);
    }
    f32x4 fif[4][2];
    if (is0) {
#pragma unroll
      for (int k = 0; k < 4; ++k) {
        fif[k][0] = *(const f32x4*)(pre0 + (k * B_ + nn) * H_ + m0 + g * 4);
        fif[k][1] = *(const f32x4*)(pre0 + (k * B_ + nn) * H_ + m0 + 16 + g * 4);
      }
    }
    __syncthreads();

    for (int base = 0; base < T_; base += 4) {
#pragma unroll
      for (int k = 0; k < 4; ++k) {
        const int s = base + k;
        const int rd = (k + 1) & 1, wr = k & 1;
        const unsigned short* hb = &hl[rd][n][0];
        s16x8 b0 = *(const s16x8*)(hb + g * 8);
        s16x8 b1 = *(const s16x8*)(hb + 32 + g * 8);
        s16x8 b2 = *(const s16x8*)(hb + 64 + g * 8);
        s16x8 b3 = *(const s16x8*)(hb + 96 + g * 8);
        if (is0) {
          f32x4 aH0 = fif[k][0], aL0 = {0.f,0.f,0.f,0.f};
          f32x4 aH1 = fif[k][1], aL1 = {0.f,0.f,0.f,0.f};
          aH0 = MFMA16(whi[0][0], b0, aH0); aL0 = MFMA16(wlo[0][0], b0, aL0);
          aH0 = MFMA16(whi[0][1], b1, aH0); aL0 = MFMA16(wlo[0][1], b1, aL0);
          aH0 = MFMA16(whi[0][2], b2, aH0); aL0 = MFMA16(wlo[0][2], b2, aL0);
          aH0 = MFMA16(whi[0][3], b3, aH0); aL0 = MFMA16(wlo[0][3], b3, aL0);
          aH1 = MFMA16(whi[1][0], b0, aH1); aL1 = MFMA16(wlo[1][0], b0, aL1);
          aH1 = MFMA16(whi[1][1], b1, aH1); aL1 = MFMA16(wlo[1][1], b1, aL1);
          aH1 = MFMA16(whi[1][2], b2, aH1); aL1 = MFMA16(wlo[1][2], b2, aL1);
          aH1 = MFMA16(whi[1][3], b3, aH1); aL1 = MFMA16(wlo[1][3], b3, aL1);
          f32x4 v0 = tanh4(aH0 + aL0), v1 = tanh4(aH1 + aL1);
          *(u32x2*)&hl[wr][n][m0 + g * 4] = pk4(v0);
          *(u32x2*)&hl[wr][n][m0 + 16 + g * 4] = pk4(v1);
          int sp = s + 4; if (sp > T_ - 1) sp = T_ - 1;   // prefetch depth 4
          fif[k][0] = *(const f32x4*)(pre0 + (sp * B_ + nn) * H_ + m0 + g * 4);
          fif[k][1] = *(const f32x4*)(pre0 + (sp * B_ + nn) * H_ + m0 + 16 + g * 4);
        } else {
          if (k == 0 && base >= 4 && lane == 0)
            __hip_atomic_fetch_add(prog1, 4u, __ATOMIC_RELEASE, __HIP_MEMORY_SCOPE_AGENT);
          if (s >= 1) {
            f32x4 v0 = c0b, v1 = c1b;
            v0 = MFMA16(whi[0][0], b0, v0); v1 = MFMA16(whi[1][0], b0, v1);
            v0 = MFMA16(whi[0][1], b1, v0); v1 = MFMA16(whi[1][1], b1, v1);
            v0 = MFMA16(whi[0][2], b2, v0); v1 = MFMA16(whi[1][2], b2, v1);
            v0 = MFMA16(whi[0][3], b3, v0); v1 = MFMA16(whi[1][3], b3, v1);
            u64x2 u0 = __builtin_bit_cast(u64x2, v0);
            u64x2 u1 = __builtin_bit_cast(u64x2, v1);
            unsigned long long* p0 = pih_g + ((size_t)((s - 1) * 8 + 2 * w) * 64 + lane) * 2;
            st_u64(p0, u0.x); st_u64(p0 + 1, u0.y);
            unsigned long long* p1 = pih_g + ((size_t)((s - 1) * 8 + 2 * w + 1) * 64 + lane) * 2;
            st_u64(p1, u1.x); st_u64(p1 + 1, u1.y);
          }
        }
        lds_barrier();
      }
    }
    // tail: stage1 computes pih[511], final release
    if (!is0) {
      const unsigned short* hb = &hl[1][n][0];
      s16x8 b0 = *(const s16x8*)(hb + g * 8);
      s16x8 b1 = *(const s16x8*)(hb + 32 + g * 8);
      s16x8 b2 = *(const s16x8*)(hb + 64 + g * 8);
      s16x8 b3 = *(const s16x8*)(hb + 96 + g * 8);
      f32x4 v0 = c0b, v1 = c1b;
      v0 = MFMA16(whi[0][0], b0, v0); v1 = MFMA16(whi[1][0], b0, v1);
      v0 = MFMA16(whi[0][1], b1, v0); v1 = MFMA16(whi[1][1], b1, v1);
      v0 = MFMA16(whi[0][2], b2, v0); v1 = MFMA16(whi[1][2], b2, v1);
      v0 = MFMA16(whi[0][3], b3, v0); v1 = MFMA16(whi[1][3], b3, v1);
      u64x2 u0 = __builtin_bit_cast(u64x2, v0);
      u64x2 u1 = __builtin_bit_cast(u64x2, v1);
      unsigned long long* p0 = pih_g + ((size_t)(511 * 8 + 2 * w) * 64 + lane) * 2;
      st_u64(p0, u0.x); st_u64(p0 + 1, u0.y);
      unsigned long long* p1 = pih_g + ((size_t)(511 * 8 + 2 * w + 1) * 64 + lane) * 2;
      st_u64(p1, u1.x); st_u64(p1 + 1, u1.y);
      if (lane == 0)
        __hip_atomic_fetch_add(prog1, 16u, __ATOMIC_RELEASE, __HIP_MEMORY_SCOPE_AGENT);
    }
  } else {
    // ---- stage2: h1 recurrence (8 waves x 1 M-tile) ----
    const int m0 = wv * 16;
    s16x8 whi[4], wlo[4];
#pragma unroll
    for (int kt = 0; kt < 4; ++kt) {
      const float* src = W_hh1 + (m0 + n) * H_ + kt * 32 + g * 8;
      s16x8 hi, lo;
#pragma unroll
      for (int j = 0; j < 8; ++j) {
        float v = src[j];
        unsigned short hb = f2b(v);
        hi[j] = (short)hb;
        lo[j] = (short)f2b(v - __uint_as_float(((unsigned int)hb) << 16));
      }
      whi[kt] = hi; wlo[kt] = lo;
    }
    __syncthreads();

    auto ld_pih = [&](int step) -> f32x4 {
      const unsigned long long* p = pih_g + ((size_t)(step * 8 + wv) * 64 + lane) * 2;
      u64x2 u; u.x = ld_u64(p); u.y = ld_u64(p + 1);
      return __builtin_bit_cast(f32x4, u);
    };

    // initial wait: producer lead 40 steps (prog1 ~= 4 * producer_base)
    if (tid == 0) {
      while (__hip_atomic_load(prog1, __ATOMIC_ACQUIRE, __HIP_MEMORY_SCOPE_AGENT) < 160u)
        __builtin_amdgcn_s_sleep(16);
    }
    __syncthreads();
    f32x4 fif[4];
#pragma unroll
    for (int k = 0; k < 4; ++k) fif[k] = ld_pih(k);

    for (int base = 0; base < T_; base += 4) {
      if ((base & 31) == 0) {
        if (tid == 0) {
          if (base > 0)
            __hip_atomic_fetch_add(prog2, 32u, __ATOMIC_RELEASE, __HIP_MEMORY_SCOPE_AGENT);
          unsigned int req = 4u * (unsigned)(base + 40);
          if (req > 2080u) req = 2080u;
          while (__hip_atomic_load(prog1, __ATOMIC_ACQUIRE, __HIP_MEMORY_SCOPE_AGENT) < req)
            __builtin_amdgcn_s_sleep(16);
        }
        __syncthreads();
      }
#pragma unroll
      for (int k = 0; k < 4; ++k) {
        const int j = base + k;
        const int rd = (k + 1) & 1, wr = k & 1;
        const unsigned short* hb = &hl[rd][n][0];
        s16x8 b0 = *(const s16x8*)(hb + g * 8);
        s16x8 b1 = *(const s16x8*)(hb + 32 + g * 8);
        s16x8 b2 = *(const s16x8*)(hb + 64 + g * 8);
        s16x8 b3 = *(const s16x8*)(hb + 96 + g * 8);
        // split K chains 2+2 (shorter dep latency)
        f32x4 aHa = MFMA16(whi[0], b0, fif[k]);
        f32x4 aHb = {0.f,0.f,0.f,0.f}, aLa = {0.f,0.f,0.f,0.f}, aLb = {0.f,0.f,0.f,0.f};
        aHb = MFMA16(whi[2], b2, aHb);
        aLa = MFMA16(wlo[0], b0, aLa);
        aLb = MFMA16(wlo[2], b2, aLb);
        aHa = MFMA16(whi[1], b1, aHa);
        aHb = MFMA16(whi[3], b3, aHb);
        aLa = MFMA16(wlo[1], b1, aLa);
        aLb = MFMA16(wlo[3], b3, aLb);
        f32x4 v = tanh4((aHa + aHb) + (aLa + aLb));
        u32x2 o = pk4(v);
        *(u32x2*)&hl[wr][n][m0 + g * 4] = o;
        if (n < 8) *(u32x2*)(h1b + ((j * B_ + n) << 7) + m0 + g * 4) = o;
        if ((j & 31) == 31)   // drain h1b stores once per 32 steps (before flag publish)
          asm volatile("s_waitcnt vmcnt(0)" ::: "memory");
        if (j + 4 < T_) fif[k] = ld_pih(j + 4);
        lds_barrier();
      }
    }
    asm volatile("s_waitcnt vmcnt(0)" ::: "memory");
    __syncthreads();
    if (tid == 0)
      __hip_atomic_fetch_add(prog2, 32u, __ATOMIC_RELEASE, __HIP_MEMORY_SCOPE_AGENT);  // -> 512
  }
}

extern "C" void kernel_launch(void* const* d_in, const int* in_sizes, int n_in,
                              void* d_out, int out_size, void* d_ws, size_t ws_size,
                              hipStream_t stream) {
  const int*   x     = (const int*)d_in[0];
  const float* emb   = (const float*)d_in[1];
  const float* W_ih0 = (const float*)d_in[2];
  const float* W_hh0 = (const float*)d_in[3];
  const float* b_ih0 = (const float*)d_in[4];
  const float* b_hh0 = (const float*)d_in[5];
  const float* W_ih1 = (const float*)d_in[6];
  const float* W_hh1 = (const float*)d_in[7];
  const float* b_ih1 = (const float*)d_in[8];
  const float* b_hh1 = (const float*)d_in[9];
  const float* fc_W  = (const float*)d_in[10];
  const float* fc_b  = (const float*)d_in[11];
  float* out = (float*)d_out;

  char* ws = (char*)d_ws;
  float*              pre0  = (float*)(ws + WS_PRE0);
  unsigned short*     h1b   = (unsigned short*)(ws + WS_H1B);
  unsigned long long* pih_g = (unsigned long long*)(ws + WS_PIH);
  unsigned int*       prog1 = (unsigned int*)(ws + WS_FLAGS);
  unsigned int*       prog2 = (unsigned int*)(ws + WS_FLAGS + 128);

  hipMemsetAsync(ws + WS_FLAGS, 0, 4096, stream);
  pre_kernel<<<256, 128, 0, stream>>>(emb, x, W_ih0, b_ih0, b_hh0, pre0);
  mega_kernel<<<2 + GRID_GEMM, 512, 0, stream>>>(pre0, W_hh0, W_ih1, W_hh1,
                                                 b_ih1, b_hh1, h1b, pih_g,
                                                 prog1, prog2, fc_W, fc_b, out);
}

// Round 8
// 547.037 us; speedup vs baseline: 6.1558x; 6.1558x over previous
//
#include <hip/hip_runtime.h>
#include <hip/hip_bf16.h>

typedef __attribute__((ext_vector_type(4))) float f32x4;
typedef __attribute__((ext_vector_type(4))) int   i32x4;
typedef __attribute__((ext_vector_type(8))) short s16x8;
typedef __attribute__((ext_vector_type(4))) unsigned short u16x4;
typedef __attribute__((ext_vector_type(2))) unsigned int  u32x2;

#define T_ 512
#define B_ 8
#define H_ 128
#define V_ 32000

// ws layout (bytes)
#define WS_PRE0   0u          // [512][8][128] f32   2MB
#define WS_H1B    (2u<<20)    // [512][8][128] bf16  1MB
#define WS_H0G    (3u<<20)    // [512][8][128] bf16  1MB
#define WS_PIH    (4u<<20)    // [512][8 wv][16 n][4 g] f32x4  4MB
#define WS_FLAGS  (8u<<20)    // prog0 @+0, prog1 @+64

// round-to-nearest-even f32 -> bf16
__device__ __forceinline__ unsigned short f2b(float f) {
  unsigned int u = __float_as_uint(f);
  u = (u + 0x7FFFu + ((u >> 16) & 1u)) >> 16;
  return (unsigned short)u;
}

__device__ __forceinline__ float hsum4(f32x4 v) { return (v.x + v.y) + (v.z + v.w); }

__device__ __forceinline__ float tanh_fast(float x) {
  float e = __expf(2.f * x);
  return 1.f - 2.f * __builtin_amdgcn_rcpf(e + 1.f);
}

__device__ __forceinline__ f32x4 tanh4(f32x4 v) {
  f32x4 r;
  r.x = tanh_fast(v.x); r.y = tanh_fast(v.y);
  r.z = tanh_fast(v.z); r.w = tanh_fast(v.w);
  return r;
}

// pack 4 f32 -> 4 bf16 (2 dwords), RNE
__device__ __forceinline__ u32x2 pk4(f32x4 v) {
  unsigned int a, b;
  asm("v_cvt_pk_bf16_f32 %0, %1, %2" : "=v"(a) : "v"(v.x), "v"(v.y));
  asm("v_cvt_pk_bf16_f32 %0, %1, %2" : "=v"(b) : "v"(v.z), "v"(v.w));
  u32x2 r; r.x = a; r.y = b; return r;
}

// barrier that does NOT drain vmcnt: LDS-only visibility + s_barrier.
__device__ __forceinline__ void lds_barrier() {
  asm volatile("s_waitcnt lgkmcnt(0)\n\ts_barrier" ::: "memory");
}

__device__ __forceinline__ unsigned int ld_flag_acq(const unsigned int* p) {
  return __hip_atomic_load(p, __ATOMIC_ACQUIRE, __HIP_MEMORY_SCOPE_AGENT);
}

#define MFMA16(A, B, C) __builtin_amdgcn_mfma_f32_16x16x32_bf16((A), (B), (C), 0, 0, 0)

__device__ __forceinline__ int swz(int row, int cc) {
  return row * 256 + ((cc ^ (row & 7)) << 4);
}

// ---------------- pre0 = emb[x] @ W_ih0^T + b_ih0 + b_hh0 ----------------
__global__ __launch_bounds__(128) void pre_kernel(const float* __restrict__ emb,
                                                  const int* __restrict__ x,
                                                  const float* __restrict__ W,
                                                  const float* __restrict__ b1,
                                                  const float* __restrict__ b2,
                                                  float* __restrict__ out) {
  const int tid = threadIdx.x;
  __shared__ alignas(16) float lds_in[H_];
  f32x4 w[32];
#pragma unroll
  for (int r = 0; r < 32; ++r) w[r] = *(const f32x4*)(W + tid * H_ + 4 * r);
  const float bsum = b1[tid] + b2[tid];
  const int m0 = blockIdx.x * 16;

  auto src_row = [&](int m) -> const float* {
    int t = m >> 3, b = m & 7;
    int tok = x[(b << 9) + t];          // x is [B,T]
    return emb + (size_t)tok * H_;
  };

  float stage = src_row(m0)[tid];
  for (int rr = 0; rr < 16; ++rr) {
    const int m = m0 + rr;
    lds_in[tid] = stage;
    __syncthreads();
    if (rr + 1 < 16) stage = src_row(m0 + rr + 1)[tid];
    f32x4 acc4 = {0.f, 0.f, 0.f, 0.f};
#pragma unroll
    for (int r = 0; r < 32; ++r) {
      f32x4 hv = *(const f32x4*)(lds_in + 4 * r);
      acc4 = __builtin_elementwise_fma(hv, w[r], acc4);
    }
    out[m * H_ + tid] = hsum4(acc4) + bsum;
    __syncthreads();
  }
}

// ---------------- fused dual-layer scan, v6: 3-CU MFMA pipeline ----------------
// block 0 = stage0: h0 recurrence (W_hh0 hi/lo), 8 waves x 1 M-tile = 8 MFMA/step.
//   h0 kept in own LDS dbuf; also stored bf16 to h0g; every 8 steps per-wave
//   vmcnt(0) + barrier + release prog0 += 8.
// block 1 = stage1: pih[j] = W_ih1 . h0[j] + b (hi-only, 4 MFMA/step). Reads h0g
//   (FIFO depth 4, all-lane acquire poll on prog0 each 4 steps); stores pih f32
//   D-frags; publishes prog1 every 8 steps.
// block 2 = stage2: h1 recurrence (W_hh1 hi/lo, 8 MFMA/step), pih FIFO-4 gated
//   on prog1; writes h1b bf16 (flushed at kernel end for the gemm kernel).
// One-way deps (0->1->2), blocks 0-2 co-resident from dispatch: deadlock-free.
#define S0_STEP(S, FIF) { \
  const int s_ = (S); \
  const int rd = (s_ + 1) & 1, wr = s_ & 1; \
  const unsigned short* hb = &hl[rd][n][0]; \
  s16x8 b0 = *(const s16x8*)(hb + g * 8); \
  s16x8 b1 = *(const s16x8*)(hb + 32 + g * 8); \
  s16x8 b2 = *(const s16x8*)(hb + 64 + g * 8); \
  s16x8 b3 = *(const s16x8*)(hb + 96 + g * 8); \
  f32x4 ha = MFMA16(whi[0], b0, FIF); \
  f32x4 hc = MFMA16(whi[2], b2, z4); \
  f32x4 la = MFMA16(wlo[0], b0, z4); \
  f32x4 lb = MFMA16(wlo[2], b2, z4); \
  ha = MFMA16(whi[1], b1, ha); \
  hc = MFMA16(whi[3], b3, hc); \
  la = MFMA16(wlo[1], b1, la); \
  lb = MFMA16(wlo[3], b3, lb); \
  f32x4 v = tanh4((ha + hc) + (la + lb)); \
  u32x2 o = pk4(v); \
  *(u32x2*)&hl[wr][n][m0 + g * 4] = o; \
  if (n < 8) *(u32x2*)(h0g + ((s_ * 8 + n) << 7) + m0 + g * 4) = o; \
  int sp = s_ + 4; if (sp > T_ - 1) sp = T_ - 1; \
  if ((s_ & 7) == 7) { \
    asm volatile("s_waitcnt vmcnt(0)" ::: "memory"); \
    (FIF) = *(const f32x4*)(pre0 + ((sp * 8 + nn) << 7) + m0 + g * 4); \
    lds_barrier(); \
    if (tid == 0) __hip_atomic_fetch_add(prog0, 8u, __ATOMIC_RELEASE, __HIP_MEMORY_SCOPE_AGENT); \
  } else { \
    (FIF) = *(const f32x4*)(pre0 + ((sp * 8 + nn) << 7) + m0 + g * 4); \
    lds_barrier(); \
  } \
}

#define S1_STEP(JJ, FB) { \
  const int j_ = (JJ); \
  f32x4 aa = MFMA16(whi[0], FB[0], biasD); \
  f32x4 ab = MFMA16(whi[2], FB[2], z4); \
  aa = MFMA16(whi[1], FB[1], aa); \
  ab = MFMA16(whi[3], FB[3], ab); \
  f32x4 v = aa + ab; \
  *(f32x4*)(pih_gf + (size_t)(j_ * 8 + wv) * 64 + n * 4 + g) = v; \
  if ((j_ & 7) == 7) { \
    asm volatile("s_waitcnt vmcnt(0)" ::: "memory"); \
    lds_barrier(); \
    if (tid == 0) __hip_atomic_fetch_add(prog1, 8u, __ATOMIC_RELEASE, __HIP_MEMORY_SCOPE_AGENT); \
  } \
  int jp = j_ + 4; \
  if (jp < T_) { \
    const unsigned short* hsrc = h0g + ((jp * 8 + nn) << 7); \
    FB[0] = *(const s16x8*)(hsrc + g * 8); \
    FB[1] = *(const s16x8*)(hsrc + 32 + g * 8); \
    FB[2] = *(const s16x8*)(hsrc + 64 + g * 8); \
    FB[3] = *(const s16x8*)(hsrc + 96 + g * 8); \
  } \
}

#define S2_STEP(J, PF) { \
  const int j_ = (J); \
  const int rd = (j_ + 1) & 1, wr = j_ & 1; \
  const unsigned short* hb = &hl[rd][n][0]; \
  s16x8 b0 = *(const s16x8*)(hb + g * 8); \
  s16x8 b1 = *(const s16x8*)(hb + 32 + g * 8); \
  s16x8 b2 = *(const s16x8*)(hb + 64 + g * 8); \
  s16x8 b3 = *(const s16x8*)(hb + 96 + g * 8); \
  f32x4 ha = MFMA16(whi[0], b0, PF); \
  f32x4 hc = MFMA16(whi[2], b2, z4); \
  f32x4 la = MFMA16(wlo[0], b0, z4); \
  f32x4 lb = MFMA16(wlo[2], b2, z4); \
  ha = MFMA16(whi[1], b1, ha); \
  hc = MFMA16(whi[3], b3, hc); \
  la = MFMA16(wlo[1], b1, la); \
  lb = MFMA16(wlo[3], b3, lb); \
  f32x4 v = tanh4((ha + hc) + (la + lb)); \
  u32x2 o = pk4(v); \
  *(u32x2*)&hl[wr][n][m0 + g * 4] = o; \
  if (n < 8) *(u32x2*)(h1b + ((j_ * 8 + n) << 7) + m0 + g * 4) = o; \
  int jp = j_ + 4; \
  if (jp < T_) (PF) = *(const f32x4*)(pih_gf + (size_t)(jp * 8 + wv) * 64 + n * 4 + g); \
  lds_barrier(); \
}

__global__ __launch_bounds__(512) __attribute__((amdgpu_waves_per_eu(2, 2)))
void fused_scan6(const float* __restrict__ pre0,
                 const float* __restrict__ W_hh0,
                 const float* __restrict__ W_ih1,
                 const float* __restrict__ W_hh1,
                 const float* __restrict__ b_ih1,
                 const float* __restrict__ b_hh1,
                 unsigned short* __restrict__ h0g,
                 float* __restrict__ pih_raw,
                 unsigned short* __restrict__ h1b,
                 unsigned int* __restrict__ prog0,
                 unsigned int* __restrict__ prog1) {
  const int bid = blockIdx.x;
  const int tid = threadIdx.x;
  const int wv = tid >> 6, lane = tid & 63;
  const int n = lane & 15, g = lane >> 4;
  const int nn = (n < 8) ? n : 7;
  const int m0 = wv * 16;
  const f32x4 z4 = {0.f, 0.f, 0.f, 0.f};
  f32x4* pih_gf = (f32x4*)pih_raw;

  __shared__ unsigned short hl[2][16][136];
  for (int i = tid; i < 2 * 16 * 136; i += 512) ((unsigned short*)hl)[i] = 0;

  if (bid == 0) {
    // ---- stage 0 ----
    s16x8 whi[4], wlo[4];
#pragma unroll
    for (int kt = 0; kt < 4; ++kt) {
      const float* src = W_hh0 + (m0 + n) * H_ + kt * 32 + g * 8;
      s16x8 hi, lo;
#pragma unroll
      for (int j = 0; j < 8; ++j) {
        float v = src[j];
        unsigned short hb16 = f2b(v);
        hi[j] = (short)hb16;
        lo[j] = (short)f2b(v - __uint_as_float(((unsigned int)hb16) << 16));
      }
      whi[kt] = hi; wlo[kt] = lo;
    }
    f32x4 f0 = *(const f32x4*)(pre0 + ((0 * 8 + nn) << 7) + m0 + g * 4);
    f32x4 f1 = *(const f32x4*)(pre0 + ((1 * 8 + nn) << 7) + m0 + g * 4);
    f32x4 f2 = *(const f32x4*)(pre0 + ((2 * 8 + nn) << 7) + m0 + g * 4);
    f32x4 f3 = *(const f32x4*)(pre0 + ((3 * 8 + nn) << 7) + m0 + g * 4);
    __syncthreads();
    for (int base = 0; base < T_; base += 4) {
      S0_STEP(base + 0, f0)
      S0_STEP(base + 1, f1)
      S0_STEP(base + 2, f2)
      S0_STEP(base + 3, f3)
    }
  } else if (bid == 1) {
    // ---- stage 1 ----
    s16x8 whi[4];
#pragma unroll
    for (int kt = 0; kt < 4; ++kt) {
      const float* src = W_ih1 + (m0 + n) * H_ + kt * 32 + g * 8;
      s16x8 hi;
#pragma unroll
      for (int j = 0; j < 8; ++j) hi[j] = (short)f2b(src[j]);
      whi[kt] = hi;
    }
    const f32x4 biasD = *(const f32x4*)(b_ih1 + m0 + g * 4) +
                        *(const f32x4*)(b_hh1 + m0 + g * 4);
    __syncthreads();
    while (ld_flag_acq(prog0) < 4u) __builtin_amdgcn_s_sleep(8);
    s16x8 fbA[4], fbB[4], fbC[4], fbD[4];
#pragma unroll
    for (int kt = 0; kt < 4; ++kt) {
      fbA[kt] = *(const s16x8*)(h0g + ((0 * 8 + nn) << 7) + kt * 32 + g * 8);
      fbB[kt] = *(const s16x8*)(h0g + ((1 * 8 + nn) << 7) + kt * 32 + g * 8);
      fbC[kt] = *(const s16x8*)(h0g + ((2 * 8 + nn) << 7) + kt * 32 + g * 8);
      fbD[kt] = *(const s16x8*)(h0g + ((3 * 8 + nn) << 7) + kt * 32 + g * 8);
    }
    for (int base = 0; base < T_; base += 4) {
      unsigned int req = (unsigned)(base + 8); if (req > 512u) req = 512u;
      while (ld_flag_acq(prog0) < req) __builtin_amdgcn_s_sleep(8);
      S1_STEP(base + 0, fbA)
      S1_STEP(base + 1, fbB)
      S1_STEP(base + 2, fbC)
      S1_STEP(base + 3, fbD)
    }
  } else {
    // ---- stage 2 ----
    s16x8 whi[4], wlo[4];
#pragma unroll
    for (int kt = 0; kt < 4; ++kt) {
      const float* src = W_hh1 + (m0 + n) * H_ + kt * 32 + g * 8;
      s16x8 hi, lo;
#pragma unroll
      for (int j = 0; j < 8; ++j) {
        float v = src[j];
        unsigned short hb16 = f2b(v);
        hi[j] = (short)hb16;
        lo[j] = (short)f2b(v - __uint_as_float(((unsigned int)hb16) << 16));
      }
      whi[kt] = hi; wlo[kt] = lo;
    }
    __syncthreads();
    while (ld_flag_acq(prog1) < 4u) __builtin_amdgcn_s_sleep(8);
    f32x4 p0 = *(const f32x4*)(pih_gf + (size_t)(0 * 8 + wv) * 64 + n * 4 + g);
    f32x4 p1 = *(const f32x4*)(pih_gf + (size_t)(1 * 8 + wv) * 64 + n * 4 + g);
    f32x4 p2 = *(const f32x4*)(pih_gf + (size_t)(2 * 8 + wv) * 64 + n * 4 + g);
    f32x4 p3 = *(const f32x4*)(pih_gf + (size_t)(3 * 8 + wv) * 64 + n * 4 + g);
    for (int base = 0; base < T_; base += 4) {
      unsigned int req = (unsigned)(base + 8); if (req > 512u) req = 512u;
      while (ld_flag_acq(prog1) < req) __builtin_amdgcn_s_sleep(8);
      S2_STEP(base + 0, p0)
      S2_STEP(base + 1, p1)
      S2_STEP(base + 2, p2)
      S2_STEP(base + 3, p3)
    }
  }
}

// ---------------- logits = h1 @ fc_W^T + fc_b (bf16 MFMA, v6) ----------------
// XCD-chunked grid; fc_W staged f32 -> bf16 in-tile (cvt_pk, no converter pass);
// LDS-transposed epilogue -> contiguous 256B row-segment nontemporal stores.
__global__ __launch_bounds__(256) void final_gemm6(const float* __restrict__ fc_W,
                                                   const unsigned short* __restrict__ h1b,
                                                   const float* __restrict__ bias,
                                                   float* __restrict__ out) {
  const int bid = blockIdx.x;
  const int x   = bid & 7;
  const int jb  = bid >> 3;
  const int mt  = jb & 31;
  const int ntl = jb >> 5;
  const int nt  = x * 32 + ntl;
  if (nt >= 250) return;

  __shared__ alignas(16) char smem[33792];   // W-stage 32KB | f32[128][66] transpose
  const int tid = threadIdx.x;
  const int bb = mt >> 2, tb = mt & 3;
  const int t0 = tb << 7;
  const int v0 = nt << 7;
  const int lane = tid & 63, wvv = tid >> 6;

  // stage fcW tile: f32 -> bf16 swizzled
#pragma unroll
  for (int it = 0; it < 8; ++it) {
    int c = it * 256 + tid;            // [0,2048) 16B chunks
    int row = c >> 4, cc = c & 15;
    const float* src = fc_W + (size_t)(v0 + row) * H_ + cc * 8;
    f32x4 va = *(const f32x4*)src;
    f32x4 vb = *(const f32x4*)(src + 4);
    u32x2 pa = pk4(va), pb = pk4(vb);
    i32x4 w16; w16.x = (int)pa.x; w16.y = (int)pa.y; w16.z = (int)pb.x; w16.w = (int)pb.y;
    *(i32x4*)(smem + swz(row, cc)) = w16;
  }
  __syncthreads();

  const int l15 = lane & 15, lg = lane >> 4;
  f32x4 acc[8][2] = {};   // [vf][mf]
#pragma unroll
  for (int kk = 0; kk < 4; ++kk) {
    const int cc = kk * 4 + lg;
    s16x8 a[8], bfr[2];
#pragma unroll
    for (int vf = 0; vf < 8; ++vf)
      a[vf] = *(const s16x8*)(smem + swz(vf * 16 + l15, cc));
#pragma unroll
    for (int mf = 0; mf < 2; ++mf) {
      int trow = t0 + wvv * 32 + mf * 16 + l15;
      bfr[mf] = *(const s16x8*)(h1b + (size_t)((trow << 3) + bb) * H_ + kk * 32 + lg * 8);
    }
#pragma unroll
    for (int vf = 0; vf < 8; ++vf)
#pragma unroll
      for (int mf = 0; mf < 2; ++mf)
        acc[vf][mf] = MFMA16(a[vf], bfr[mf], acc[vf][mf]);
  }

#pragma unroll
  for (int vf = 0; vf < 8; ++vf) {
    f32x4 bv = *(const f32x4*)(bias + v0 + vf * 16 + (lg << 2));
#pragma unroll
    for (int mf = 0; mf < 2; ++mf) acc[vf][mf] += bv;
  }

  float* tbf = (float*)smem;
#pragma unroll
  for (int p = 0; p < 2; ++p) {
    __syncthreads();
#pragma unroll
    for (int q = 0; q < 4; ++q) {
      const int vf = p * 4 + q;
#pragma unroll
      for (int mf = 0; mf < 2; ++mf) {
        int t = wvv * 32 + mf * 16 + l15;
        int vl = q * 16 + lg * 4;
        *(f32x4*)(tbf + t * 66 + vl) = acc[vf][mf];
      }
    }
    __syncthreads();
#pragma unroll
    for (int it = 0; it < 8; ++it) {
      int row = it * 16 + (tid >> 4);
      int col = (tid & 15) * 4;
      f32x4 val = *(const f32x4*)(tbf + row * 66 + col);
      const size_t off = (size_t)((bb << 9) + t0 + row) * V_ + v0 + p * 64 + col;
      __builtin_nontemporal_store(val, (f32x4*)(out + off));
    }
  }
}

extern "C" void kernel_launch(void* const* d_in, const int* in_sizes, int n_in,
                              void* d_out, int out_size, void* d_ws, size_t ws_size,
                              hipStream_t stream) {
  const int*   x     = (const int*)d_in[0];
  const float* emb   = (const float*)d_in[1];
  const float* W_ih0 = (const float*)d_in[2];
  const float* W_hh0 = (const float*)d_in[3];
  const float* b_ih0 = (const float*)d_in[4];
  const float* b_hh0 = (const float*)d_in[5];
  const float* W_ih1 = (const float*)d_in[6];
  const float* W_hh1 = (const float*)d_in[7];
  const float* b_ih1 = (const float*)d_in[8];
  const float* b_hh1 = (const float*)d_in[9];
  const float* fc_W  = (const float*)d_in[10];
  const float* fc_b  = (const float*)d_in[11];
  float* out = (float*)d_out;

  char* ws = (char*)d_ws;
  float*          pre0  = (float*)(ws + WS_PRE0);
  unsigned short* h1b   = (unsigned short*)(ws + WS_H1B);
  unsigned short* h0g   = (unsigned short*)(ws + WS_H0G);
  float*          pih   = (float*)(ws + WS_PIH);
  unsigned int*   prog0 = (unsigned int*)(ws + WS_FLAGS);
  unsigned int*   prog1 = (unsigned int*)(ws + WS_FLAGS + 64);

  hipMemsetAsync(ws + WS_FLAGS, 0, 4096, stream);
  pre_kernel<<<256, 128, 0, stream>>>(emb, x, W_ih0, b_ih0, b_hh0, pre0);
  fused_scan6<<<3, 512, 0, stream>>>(pre0, W_hh0, W_ih1, W_hh1, b_ih1, b_hh1,
                                     h0g, pih, h1b, prog0, prog1);
  final_gemm6<<<8192, 256, 0, stream>>>(fc_W, h1b, fc_b, out);
}